// Round 13
// baseline (199.426 us; speedup 1.0000x reference)
//
#include <hip/hip_runtime.h>

#define N_    64
#define HW_   240
#define H1_   120
#define H2_   60
#define C0_   3
#define C1_   32
#define C2_   64
#define C3_   128
#define HEAD_ 1280

typedef unsigned short US;
typedef short bf16x8 __attribute__((ext_vector_type(8)));
typedef float f32x16 __attribute__((ext_vector_type(16)));

__device__ __forceinline__ US f2bf(float f) {
  union { float f; unsigned u; } v; v.f = f;
  unsigned r = v.u + 0x7FFF + ((v.u >> 16) & 1);  // RNE
  return (US)(r >> 16);
}

// h1q parity-split padded NHWC bf16: [n][row 122][parity 2][xh 62][32ch].
// h1 pixel (gy,gx): row = gy+1; gx even=2m -> plane0[m]; gx odd=2m-1 -> plane1[m].
#define H1Q_ROW 3968
#define H1Q_PL  1984

// ---------------------------------------------------------------------------
// K0: prep — zero h1q pad cells (uint4); w1 -> wt1 [ky][kx][oc][ic] bf16;
// w2 -> wt2 [oc][ic] bf16; w_stem -> wt0 [oc][k32] bf16 (k>=27 zero);
// zero gap.
// ---------------------------------------------------------------------------
#define ZCHN   368                 // zero-chunks per n (124+124+120)
#define ZTOT   (64 * ZCHN * 4)     // 94208
__global__ __launch_bounds__(256) void k0_prep(
    const float* __restrict__ w1, const float* __restrict__ w2,
    const float* __restrict__ w0,
    US* __restrict__ h1q, US* __restrict__ wt1, US* __restrict__ wt2,
    US* __restrict__ wt0, float* __restrict__ gap) {
  int gid = blockIdx.x * 256 + threadIdx.x;
  if (gid < ZTOT) {
    int c = gid >> 2, q = gid & 3;
    int n = c / ZCHN, cc = c % ZCHN;
    long off; int y;
    if (cc < 124)      { y = 0;   off = (long)cc * 32; }
    else if (cc < 248) { y = 121; off = (long)(cc - 124) * 32; }
    else               { y = cc - 247; off = H1Q_PL; }   // p1 m=0, rows 1..120
    uint4 z; z.x = z.y = z.z = z.w = 0u;
    *(uint4*)(h1q + ((long)(n * 122 + y)) * H1Q_ROW + off + q * 8) = z;
  } else if (gid < ZTOT + 18432) {
    int e = gid - ZTOT;                       // w1 flat [oc][ic][ky][kx]
    int oc = e / 288, ic = (e / 9) % 32, ky = (e / 3) % 3, kx = e % 3;
    wt1[((ky * 3 + kx) * 64 + oc) * 32 + ic] = f2bf(w1[e]);
  } else if (gid < ZTOT + 18432 + 8192) {
    int e = gid - (ZTOT + 18432);
    wt2[e] = f2bf(w2[e]);
  } else if (gid < ZTOT + 18432 + 8192 + 1024) {
    int e = gid - (ZTOT + 18432 + 8192);      // e = oc*32 + k
    int oc = e >> 5, k = e & 31;
    wt0[e] = (k < 27) ? f2bf(w0[oc * 27 + k]) : (US)0;
  } else if (gid < ZTOT + 18432 + 8192 + 1024 + 8192) {
    gap[gid - (ZTOT + 18432 + 8192 + 1024)] = 0.f;
  }
}

// ---------------------------------------------------------------------------
// K1: stem conv 3->32 via MFMA im2col, 4 output rows per block.
// Stage 9 input rows x 3ch f32 into LDS (26.4 KB, amortized over 4 rows).
// Wave wv owns output row 4*bx+wv as 4 independent tile-chains (8 MFMAs,
// shared B). Direct stores: D-layout lanes are oc-contiguous -> each 2-B
// store instruction covers full 64-B sectors (NOT the R6 stride trap).
// Grid (30, 64).
// ---------------------------------------------------------------------------
#define XSW 244
__global__ __launch_bounds__(256) void k1_mfma(
    const float* __restrict__ x, const US* __restrict__ wt0,
    const float* __restrict__ alpha, const float* __restrict__ beta,
    US* __restrict__ h1q) {
  __shared__ float xs[3 * 9 * XSW];   // [ic][9 rows][244]; xs[..][i]=row[i-1]
  int bx = blockIdx.x, n = blockIdx.y;
  int iy0 = 8 * bx - 1;
  const float* xn = x + (long)n * C0_ * HW_ * HW_;
  for (int e = threadIdx.x; e < 3 * 9 * XSW; e += 256) {
    int col = e % XSW, seg = e / XSW;
    int ic = seg / 9, rr = seg % 9;
    int iy = iy0 + rr, ix = col - 1;
    float v = 0.f;
    if (iy >= 0 && ix >= 0 && ix < HW_)
      v = xn[(long)ic * HW_ * HW_ + iy * HW_ + ix];
    xs[e] = v;
  }
  __syncthreads();

  int t = threadIdx.x, wv = t >> 6, l = t & 63;
  int lane31 = l & 31, half = l >> 5;
  int y = bx * 4 + wv;                 // this wave's output row
  int oc = lane31;

  const US* wb = wt0 + lane31 * 32 + half * 8;   // B: oc = lane31
  bf16x8 b0 = *(const bf16x8*)(wb);
  bf16x8 b1 = *(const bf16x8*)(wb + 16);

  // per-j LDS segment offsets (k = m*16 + half*8 + j)
  int joff[16]; bool jok[16];
#pragma unroll
  for (int m = 0; m < 2; m++)
#pragma unroll
    for (int j = 0; j < 8; j++) {
      int k = m * 16 + half * 8 + j;
      bool ok = k < 27;
      int ic = ok ? k / 9 : 0;
      int rem = k - ic * 9;
      int ky = rem / 3, kx = rem - ky * 3;
      joff[m * 8 + j] = (ic * 9 + 2 * wv + ky) * XSW + kx;
      jok[m * 8 + j] = ok;
    }

  float al = alpha[oc], be = beta[oc];
  long rowb = ((long)(n * 122 + y + 1)) * H1Q_ROW;

  f32x16 acc[4];
  bf16x8 a0[4], a1[4];
#pragma unroll
  for (int c = 0; c < 4; c++) {
    int ox = c * 32 + lane31;
    int oxc = ox < H1_ ? ox : (H1_ - 1);
    int base = 2 * oxc;
#pragma unroll
    for (int j = 0; j < 8; j++) {
      a0[c][j] = (short)(jok[j]     ? f2bf(xs[joff[j] + base])     : 0);
      a1[c][j] = (short)(jok[8 + j] ? f2bf(xs[joff[8 + j] + base]) : 0);
    }
#pragma unroll
    for (int i = 0; i < 16; i++) acc[c][i] = 0.f;
  }
#pragma unroll
  for (int c = 0; c < 4; c++)
    acc[c] = __builtin_amdgcn_mfma_f32_32x32x16_bf16(a0[c], b0, acc[c], 0, 0, 0);
#pragma unroll
  for (int c = 0; c < 4; c++)
    acc[c] = __builtin_amdgcn_mfma_f32_32x32x16_bf16(a1[c], b1, acc[c], 0, 0, 0);

#pragma unroll
  for (int c = 0; c < 4; c++) {
#pragma unroll
    for (int r = 0; r < 16; r++) {
      int row = (r & 3) + 8 * (r >> 2) + 4 * half;
      int px = c * 32 + row;
      if (px < H1_) {
        float v = fmaxf(fmaf(acc[c][r], al, be), 0.f);
        long addr = rowb + ((px & 1) ? H1Q_PL : 0) + (long)((px + 1) >> 1) * 32 + oc;
        h1q[addr] = f2bf(v);
      }
    }
  }
}

// ---------------------------------------------------------------------------
// K2: FUSED conv2 + conv3 + BN/ReLU + GAP. 256-px tiles, 4 independent
// Stage-A chains per wave (72 MFMA, B shared 4-ways, 2x outstanding loads).
// Stage B: wave owns 64 px (2 af-sets) x 128 oc2. Grid (15, 64).
// ---------------------------------------------------------------------------
#define TS 72
__global__ __launch_bounds__(256) void k2_fused(
    const US* __restrict__ h1q, const US* __restrict__ wt1,
    const US* __restrict__ wt2,
    const float* __restrict__ a1, const float* __restrict__ b1,
    const float* __restrict__ a2, const float* __restrict__ b2,
    float* __restrict__ gap) {
  __shared__ US tile[256 * TS];  // 36864 B
  int n = blockIdx.y, tileb = blockIdx.x;
  int t = threadIdx.x, w = t >> 6, l = t & 63;
  int wm = w & 1, wn = w >> 1;
  int lane31 = l & 31, half = l >> 5;
  int oc = wn * 32 + lane31;

  // 4 px chains for this wave
  int yy[4], xx[4];
#pragma unroll
  for (int c = 0; c < 4; c++) {
    int p = tileb * 256 + wm * 128 + c * 32 + lane31;
    int pc = p < 3600 ? p : 3599;
    yy[c] = pc / 60; xx[c] = pc % 60;
  }

  f32x16 acc[4];
#pragma unroll
  for (int c = 0; c < 4; c++)
#pragma unroll
    for (int i = 0; i < 16; i++) acc[c][i] = 0.f;

#pragma unroll
  for (int ky = 0; ky < 3; ky++) {
    const US* ab[4];
#pragma unroll
    for (int c = 0; c < 4; c++)
      ab[c] = h1q + ((long)(n * 122 + 2 * yy[c] + ky)) * H1Q_ROW
                  + (long)xx[c] * 32 + half * 8;
    const US* wk = wt1 + (ky * 3) * (64 * 32) + oc * 32 + half * 8;
#pragma unroll
    for (int kx = 0; kx < 3; kx++) {
      long aoff = (kx == 1) ? 0 : (kx == 0 ? H1Q_PL : (H1Q_PL + 32));
      const US* bp = wk + kx * (64 * 32);
#pragma unroll
      for (int cc = 0; cc < 2; cc++) {
        bf16x8 bv = *(const bf16x8*)(bp + cc * 16);
#pragma unroll
        for (int c = 0; c < 4; c++) {
          bf16x8 av = *(const bf16x8*)(ab[c] + aoff + cc * 16);
          acc[c] = __builtin_amdgcn_mfma_f32_32x32x16_bf16(av, bv, acc[c], 0, 0, 0);
        }
      }
    }
  }
  {  // h2 tiles -> LDS (bf16, BN+ReLU applied)
    float al = a1[oc], be = b1[oc];
#pragma unroll
    for (int c = 0; c < 4; c++)
#pragma unroll
      for (int r = 0; r < 16; r++) {
        int row = (r & 3) + 8 * (r >> 2) + 4 * half;
        float v = fmaxf(fmaf(acc[c][r], al, be), 0.f);
        tile[(wm * 128 + c * 32 + row) * TS + oc] = f2bf(v);
      }
  }
  __syncthreads();

  // Stage B: wave w owns 64 px (2 sets of 32) x 128 oc2; af loaded once.
  int base_px = tileb * 256 + w * 64;
  bf16x8 af[2][4];
#pragma unroll
  for (int s = 0; s < 2; s++) {
    const US* ap = tile + (w * 64 + s * 32 + lane31) * TS + half * 8;
#pragma unroll
    for (int c = 0; c < 4; c++) af[s][c] = *(const bf16x8*)(ap + c * 16);
  }

#pragma unroll
  for (int nt = 0; nt < 4; nt++) {
    int oc2 = nt * 32 + lane31;
    const US* bb = wt2 + oc2 * 64 + half * 8;
    bf16x8 bv[4];
#pragma unroll
    for (int c = 0; c < 4; c++) bv[c] = *(const bf16x8*)(bb + c * 16);
    float al2 = a2[oc2], be2 = b2[oc2];
    float s = 0.f;
#pragma unroll
    for (int st = 0; st < 2; st++) {
      f32x16 acc2;
#pragma unroll
      for (int i = 0; i < 16; i++) acc2[i] = 0.f;
#pragma unroll
      for (int c = 0; c < 4; c++)
        acc2 = __builtin_amdgcn_mfma_f32_32x32x16_bf16(af[st][c], bv[c], acc2, 0, 0, 0);
      int pxb = base_px + st * 32;
      if (pxb + 31 < 3600) {
#pragma unroll
        for (int r = 0; r < 16; r++) s += fmaxf(fmaf(acc2[r], al2, be2), 0.f);
      } else {
#pragma unroll
        for (int r = 0; r < 16; r++) {
          int row = (r & 3) + 8 * (r >> 2) + 4 * half;
          if (pxb + row < 3600) s += fmaxf(fmaf(acc2[r], al2, be2), 0.f);
        }
      }
    }
    s += __shfl_xor(s, 32);
    if (half == 0) atomicAdd(gap + n * C3_ + oc2, s);
  }
}

// ---------------------------------------------------------------------------
// K4: head — gap/3600 @ w_head^T, BN fold + ReLU (f32).
// ---------------------------------------------------------------------------
__global__ __launch_bounds__(256) void k4_head(
    const float* __restrict__ gap, const float* __restrict__ wh,
    const float* __restrict__ alpha, const float* __restrict__ beta,
    float* __restrict__ out) {
  __shared__ float g[C3_];
  int n = blockIdx.y;
  int o = blockIdx.x * 256 + threadIdx.x;
  if (threadIdx.x < C3_)
    g[threadIdx.x] = gap[n * C3_ + threadIdx.x] * (1.f / 3600.f);
  __syncthreads();
  const float* wr = wh + (long)o * C3_;
  float acc = 0.f;
#pragma unroll 8
  for (int c = 0; c < C3_; c += 4) {
    float4 wv = *(const float4*)(wr + c);
    acc = fmaf(wv.x, g[c],     acc);
    acc = fmaf(wv.y, g[c + 1], acc);
    acc = fmaf(wv.z, g[c + 2], acc);
    acc = fmaf(wv.w, g[c + 3], acc);
  }
  out[n * HEAD_ + o] = fmaxf(fmaf(acc, alpha[o], beta[o]), 0.f);
}

// ---------------------------------------------------------------------------
extern "C" void kernel_launch(void* const* d_in, const int* in_sizes, int n_in,
                              void* d_out, int out_size, void* d_ws,
                              size_t ws_size, hipStream_t stream) {
  const float* x      = (const float*)d_in[0];
  const float* w_stem = (const float*)d_in[1];
  const float* a_stem = (const float*)d_in[2];
  const float* b_stem = (const float*)d_in[3];
  const float* w1     = (const float*)d_in[4];
  const float* a1     = (const float*)d_in[5];
  const float* b1     = (const float*)d_in[6];
  const float* w2     = (const float*)d_in[7];
  const float* a2     = (const float*)d_in[8];
  const float* b2     = (const float*)d_in[9];
  const float* wh     = (const float*)d_in[10];
  const float* ah     = (const float*)d_in[11];
  const float* bh     = (const float*)d_in[12];
  float* out = (float*)d_out;

  US* h1q = (US*)d_ws;                                   // 64*122*3968
  US* wt1 = h1q + (size_t)N_ * 122 * H1Q_ROW;            // 9*64*32
  US* wt2 = wt1 + 9 * 64 * 32;                           // 128*64
  US* wt0 = wt2 + C3_ * C2_;                             // 32*32
  float* gap = (float*)(wt0 + 1024);                     // 64*128 f32

  {  // K0 prep
    int total = ZTOT + 18432 + 8192 + 1024 + 8192;
    k0_prep<<<(total + 255) / 256, 256, 0, stream>>>(w1, w2, w_stem, h1q,
                                                     wt1, wt2, wt0, gap);
  }
  {  // K1 MFMA stem: 4 rows per block
    dim3 grid(30, N_);
    k1_mfma<<<grid, 256, 0, stream>>>(x, wt0, a_stem, b_stem, h1q);
  }
  {  // K2 fused conv2+conv3+GAP, 256-px tiles
    dim3 grid(15, N_);
    k2_fused<<<grid, 256, 0, stream>>>(h1q, wt1, wt2, a1, b1, a2, b2, gap);
  }
  {  // K4
    dim3 grid(HEAD_ / 256, N_);
    k4_head<<<grid, 256, 0, stream>>>(gap, wh, ah, bh, out);
  }
}

// Round 14
// 172.744 us; speedup vs baseline: 1.1545x; 1.1545x over previous
//
#include <hip/hip_runtime.h>

#define N_    64
#define HW_   240
#define H1_   120
#define H2_   60
#define C0_   3
#define C1_   32
#define C2_   64
#define C3_   128
#define HEAD_ 1280

typedef unsigned short US;
typedef short bf16x8 __attribute__((ext_vector_type(8)));
typedef float f32x16 __attribute__((ext_vector_type(16)));

__device__ __forceinline__ US f2bf(float f) {
  union { float f; unsigned u; } v; v.f = f;
  unsigned r = v.u + 0x7FFF + ((v.u >> 16) & 1);  // RNE
  return (US)(r >> 16);
}

// h1q parity-split padded NHWC bf16: [n][row 122][parity 2][xh 62][32ch].
// h1 pixel (gy,gx): row = gy+1; gx even=2m -> plane0[m]; gx odd=2m-1 -> plane1[m].
#define H1Q_ROW 3968
#define H1Q_PL  1984

// ---------------------------------------------------------------------------
// K0: prep — zero h1q pad cells (uint4); w1 -> wt1 [ky][kx][oc][ic] bf16;
// w2 -> wt2 [oc][ic] bf16; w_stem -> wt0 [oc][k32] bf16 (k>=27 zero);
// zero gap. (R12 config, unchanged.)
// ---------------------------------------------------------------------------
#define ZCHN   368                 // zero-chunks per n (124+124+120)
#define ZTOT   (64 * ZCHN * 4)     // 94208
__global__ __launch_bounds__(256) void k0_prep(
    const float* __restrict__ w1, const float* __restrict__ w2,
    const float* __restrict__ w0,
    US* __restrict__ h1q, US* __restrict__ wt1, US* __restrict__ wt2,
    US* __restrict__ wt0, float* __restrict__ gap) {
  int gid = blockIdx.x * 256 + threadIdx.x;
  if (gid < ZTOT) {
    int c = gid >> 2, q = gid & 3;
    int n = c / ZCHN, cc = c % ZCHN;
    long off; int y;
    if (cc < 124)      { y = 0;   off = (long)cc * 32; }
    else if (cc < 248) { y = 121; off = (long)(cc - 124) * 32; }
    else               { y = cc - 247; off = H1Q_PL; }   // p1 m=0, rows 1..120
    uint4 z; z.x = z.y = z.z = z.w = 0u;
    *(uint4*)(h1q + ((long)(n * 122 + y)) * H1Q_ROW + off + q * 8) = z;
  } else if (gid < ZTOT + 18432) {
    int e = gid - ZTOT;                       // w1 flat [oc][ic][ky][kx]
    int oc = e / 288, ic = (e / 9) % 32, ky = (e / 3) % 3, kx = e % 3;
    wt1[((ky * 3 + kx) * 64 + oc) * 32 + ic] = f2bf(w1[e]);
  } else if (gid < ZTOT + 18432 + 8192) {
    int e = gid - (ZTOT + 18432);
    wt2[e] = f2bf(w2[e]);
  } else if (gid < ZTOT + 18432 + 8192 + 1024) {
    int e = gid - (ZTOT + 18432 + 8192);      // e = oc*32 + k
    int oc = e >> 5, k = e & 31;
    wt0[e] = (k < 27) ? f2bf(w0[oc * 27 + k]) : (US)0;
  } else if (gid < ZTOT + 18432 + 8192 + 1024 + 8192) {
    gap[gid - (ZTOT + 18432 + 8192 + 1024)] = 0.f;
  }
}

// ---------------------------------------------------------------------------
// K1: stem conv 3->32 via MFMA im2col (K=27 pad 32 = 2 MFMAs/tile).
// R12 structure LOCKED (1 output row per block, grid 120x64; R13's 4-row
// variant: 829K LDS bank conflicts + fewer blocks -> 74us, reverted).
// This round's only change: xs staging vectorized — layout shifted +4
// (XSW 248) so global float4 loads (ix=4m) and LDS float4 writes (4+4m) are
// both 16B-aligned: 8.6 scalar loads/thread -> 2.2 float4 loads/thread.
// ---------------------------------------------------------------------------
#define XSW 248
__global__ __launch_bounds__(256) void k1_mfma(
    const float* __restrict__ x, const US* __restrict__ wt0,
    const float* __restrict__ alpha, const float* __restrict__ beta,
    US* __restrict__ h1q) {
  __shared__ float xs[3 * 3 * XSW];   // [ic][r][248]; xs[seg][4+ix] = row[ix]
  __shared__ US ot[128 * 32];         // [px][oc] bf16
  int y = blockIdx.x, n = blockIdx.y;
  int iy0 = 2 * y - 1;
  const float* xn = x + (long)n * C0_ * HW_ * HW_;
  // interior: 9 segs x 60 float4
  for (int e = threadIdx.x; e < 540; e += 256) {
    int m = e % 60, seg = e / 60;
    int ic = seg / 3, r = seg % 3;
    int iy = iy0 + r;                  // max 239, only y==0,r==0 gives -1
    float4 v; v.x = v.y = v.z = v.w = 0.f;
    if (iy >= 0) v = *(const float4*)(xn + (long)ic * HW_ * HW_ + iy * HW_ + 4 * m);
    *(float4*)(xs + seg * XSW + 4 + 4 * m) = v;
  }
  // boundary zeros: cols 0..3 and 244..247 per seg
  if (threadIdx.x < 18) {
    int seg = threadIdx.x >> 1, end = threadIdx.x & 1;
    float4 z; z.x = z.y = z.z = z.w = 0.f;
    *(float4*)(xs + seg * XSW + (end ? 244 : 0)) = z;
  }
  __syncthreads();

  int t = threadIdx.x, wv = t >> 6, l = t & 63;
  int lane31 = l & 31, half = l >> 5;
  int ox = wv * 32 + lane31;
  int oxc = ox < H1_ ? ox : (H1_ - 1);

  // A fragments: k = m*16 + half*8 + j; value = xs[seg(k)][3 + 2*oxc + kx]
  float fa[16];
#pragma unroll
  for (int m = 0; m < 2; m++)
#pragma unroll
    for (int j = 0; j < 8; j++) {
      int k = m * 16 + half * 8 + j;
      float v = 0.f;
      if (k < 27) {
        int ic = k / 9, rem = k - ic * 9;
        int ky = rem / 3, kx = rem - ky * 3;
        v = xs[(ic * 3 + ky) * XSW + 3 + 2 * oxc + kx];
      }
      fa[m * 8 + j] = v;
    }
  bf16x8 a0, a1;
#pragma unroll
  for (int j = 0; j < 8; j++) {
    a0[j] = (short)f2bf(fa[j]);
    a1[j] = (short)f2bf(fa[8 + j]);
  }
  const US* wb = wt0 + lane31 * 32 + half * 8;   // oc = lane31
  bf16x8 b0 = *(const bf16x8*)(wb);
  bf16x8 b1 = *(const bf16x8*)(wb + 16);

  f32x16 acc;
#pragma unroll
  for (int i = 0; i < 16; i++) acc[i] = 0.f;
  acc = __builtin_amdgcn_mfma_f32_32x32x16_bf16(a0, b0, acc, 0, 0, 0);
  acc = __builtin_amdgcn_mfma_f32_32x32x16_bf16(a1, b1, acc, 0, 0, 0);

  int oc = lane31;
  float al = alpha[oc], be = beta[oc];
#pragma unroll
  for (int r = 0; r < 16; r++) {
    int row = (r & 3) + 8 * (r >> 2) + 4 * half;   // px within tile
    float v = fmaxf(fmaf(acc[r], al, be), 0.f);
    ot[(wv * 32 + row) * 32 + oc] = f2bf(v);
  }
  __syncthreads();

  // store 120 px * 64 B as parity-split full chunks; 480 uint4 total
  long rowb = ((long)(n * 122 + y + 1)) * H1Q_ROW;
  for (int u = t; u < 480; u += 256) {
    int px = u >> 2, q = u & 3;
    int pl = px & 1;
    int m = (px + 1) >> 1;
    long addr = rowb + (pl ? H1Q_PL : 0) + (long)m * 32 + q * 8;
    *(uint4*)(h1q + addr) = *(const uint4*)(ot + px * 32 + q * 8);
  }
}

// ---------------------------------------------------------------------------
// K2: FUSED conv2 + conv3 + BN/ReLU + GAP. R12/R11 config LOCKED:
// 128-px tile, 2 Stage-A chains/wave, VGPR 52, 18 KB LDS, grid (29,64).
// (R13's 256-px/4-chain: VGPR 84 -> occupancy 22% -> 69us, reverted.)
// ---------------------------------------------------------------------------
#define TS 72
__global__ __launch_bounds__(256) void k2_fused(
    const US* __restrict__ h1q, const US* __restrict__ wt1,
    const US* __restrict__ wt2,
    const float* __restrict__ a1, const float* __restrict__ b1,
    const float* __restrict__ a2, const float* __restrict__ b2,
    float* __restrict__ gap) {
  __shared__ US tile[128 * TS];  // 18432 B
  int n = blockIdx.y, tileb = blockIdx.x;
  int t = threadIdx.x, w = t >> 6, l = t & 63;
  int wm = w & 1, wn = w >> 1;
  int lane31 = l & 31, half = l >> 5;
  int oc = wn * 32 + lane31;

  int pxb0 = tileb * 128 + wm * 64;
  int pxb1 = pxb0 + 32;
  int p0 = pxb0 + lane31; int pc0 = p0 < 3600 ? p0 : 3599;
  int p1 = pxb1 + lane31; int pc1 = p1 < 3600 ? p1 : 3599;
  int y0 = pc0 / 60, xx0 = pc0 % 60;
  int y1 = pc1 / 60, xx1 = pc1 % 60;

  f32x16 accA, accB;
#pragma unroll
  for (int i = 0; i < 16; i++) { accA[i] = 0.f; accB[i] = 0.f; }

#pragma unroll
  for (int ky = 0; ky < 3; ky++) {
    const US* c0a1 = h1q + ((long)(n * 122 + 2 * y0 + ky)) * H1Q_ROW
                         + (long)xx0 * 32 + half * 8;
    const US* c1a1 = h1q + ((long)(n * 122 + 2 * y1 + ky)) * H1Q_ROW
                         + (long)xx1 * 32 + half * 8;
    const US* wk = wt1 + (ky * 3) * (64 * 32) + oc * 32 + half * 8;
#pragma unroll
    for (int kx = 0; kx < 3; kx++) {
      long aoff = (kx == 1) ? 0 : (kx == 0 ? H1Q_PL : (H1Q_PL + 32));
      const US* bp = wk + kx * (64 * 32);
#pragma unroll
      for (int c = 0; c < 2; c++) {
        bf16x8 bv  = *(const bf16x8*)(bp + c * 16);
        bf16x8 av0 = *(const bf16x8*)(c0a1 + aoff + c * 16);
        bf16x8 av1 = *(const bf16x8*)(c1a1 + aoff + c * 16);
        accA = __builtin_amdgcn_mfma_f32_32x32x16_bf16(av0, bv, accA, 0, 0, 0);
        accB = __builtin_amdgcn_mfma_f32_32x32x16_bf16(av1, bv, accB, 0, 0, 0);
      }
    }
  }
  {
    float al = a1[oc], be = b1[oc];
#pragma unroll
    for (int r = 0; r < 16; r++) {
      int row = (r & 3) + 8 * (r >> 2) + 4 * half;
      float vA = fmaxf(fmaf(accA[r], al, be), 0.f);
      float vB = fmaxf(fmaf(accB[r], al, be), 0.f);
      tile[(wm * 64 + row) * TS + oc] = f2bf(vA);
      tile[(wm * 64 + 32 + row) * TS + oc] = f2bf(vB);
    }
  }
  __syncthreads();

  int base_px = tileb * 128 + w * 32;
  const US* abase2 = tile + (w * 32 + lane31) * TS + half * 8;
  bf16x8 af[4];
#pragma unroll
  for (int c = 0; c < 4; c++) af[c] = *(const bf16x8*)(abase2 + c * 16);

#pragma unroll
  for (int nt = 0; nt < 4; nt++) {
    int oc2 = nt * 32 + lane31;
    const US* bb = wt2 + oc2 * 64 + half * 8;
    f32x16 acc2;
#pragma unroll
    for (int i = 0; i < 16; i++) acc2[i] = 0.f;
#pragma unroll
    for (int c = 0; c < 4; c++) {
      bf16x8 bv = *(const bf16x8*)(bb + c * 16);
      acc2 = __builtin_amdgcn_mfma_f32_32x32x16_bf16(af[c], bv, acc2, 0, 0, 0);
    }
    float al2 = a2[oc2], be2 = b2[oc2];
    float s = 0.f;
    if (base_px + 31 < 3600) {
#pragma unroll
      for (int r = 0; r < 16; r++) s += fmaxf(fmaf(acc2[r], al2, be2), 0.f);
    } else {
#pragma unroll
      for (int r = 0; r < 16; r++) {
        int row = (r & 3) + 8 * (r >> 2) + 4 * half;
        if (base_px + row < 3600) s += fmaxf(fmaf(acc2[r], al2, be2), 0.f);
      }
    }
    s += __shfl_xor(s, 32);
    if (half == 0) atomicAdd(gap + n * C3_ + oc2, s);
  }
}

// ---------------------------------------------------------------------------
// K4: head — gap/3600 @ w_head^T, BN fold + ReLU (f32).
// ---------------------------------------------------------------------------
__global__ __launch_bounds__(256) void k4_head(
    const float* __restrict__ gap, const float* __restrict__ wh,
    const float* __restrict__ alpha, const float* __restrict__ beta,
    float* __restrict__ out) {
  __shared__ float g[C3_];
  int n = blockIdx.y;
  int o = blockIdx.x * 256 + threadIdx.x;
  if (threadIdx.x < C3_)
    g[threadIdx.x] = gap[n * C3_ + threadIdx.x] * (1.f / 3600.f);
  __syncthreads();
  const float* wr = wh + (long)o * C3_;
  float acc = 0.f;
#pragma unroll 8
  for (int c = 0; c < C3_; c += 4) {
    float4 wv = *(const float4*)(wr + c);
    acc = fmaf(wv.x, g[c],     acc);
    acc = fmaf(wv.y, g[c + 1], acc);
    acc = fmaf(wv.z, g[c + 2], acc);
    acc = fmaf(wv.w, g[c + 3], acc);
  }
  out[n * HEAD_ + o] = fmaxf(fmaf(acc, alpha[o], beta[o]), 0.f);
}

// ---------------------------------------------------------------------------
extern "C" void kernel_launch(void* const* d_in, const int* in_sizes, int n_in,
                              void* d_out, int out_size, void* d_ws,
                              size_t ws_size, hipStream_t stream) {
  const float* x      = (const float*)d_in[0];
  const float* w_stem = (const float*)d_in[1];
  const float* a_stem = (const float*)d_in[2];
  const float* b_stem = (const float*)d_in[3];
  const float* w1     = (const float*)d_in[4];
  const float* a1     = (const float*)d_in[5];
  const float* b1     = (const float*)d_in[6];
  const float* w2     = (const float*)d_in[7];
  const float* a2     = (const float*)d_in[8];
  const float* b2     = (const float*)d_in[9];
  const float* wh     = (const float*)d_in[10];
  const float* ah     = (const float*)d_in[11];
  const float* bh     = (const float*)d_in[12];
  float* out = (float*)d_out;

  US* h1q = (US*)d_ws;                                   // 64*122*3968
  US* wt1 = h1q + (size_t)N_ * 122 * H1Q_ROW;            // 9*64*32
  US* wt2 = wt1 + 9 * 64 * 32;                           // 128*64
  US* wt0 = wt2 + C3_ * C2_;                             // 32*32
  float* gap = (float*)(wt0 + 1024);                     // 64*128 f32

  {  // K0 prep
    int total = ZTOT + 18432 + 8192 + 1024 + 8192;
    k0_prep<<<(total + 255) / 256, 256, 0, stream>>>(w1, w2, w_stem, h1q,
                                                     wt1, wt2, wt0, gap);
  }
  {  // K1 MFMA stem: one block per (row, n)
    dim3 grid(H1_, N_);
    k1_mfma<<<grid, 256, 0, stream>>>(x, wt0, a_stem, b_stem, h1q);
  }
  {  // K2 fused conv2+conv3+GAP, 128-px tiles
    dim3 grid(29, N_);
    k2_fused<<<grid, 256, 0, stream>>>(h1q, wt1, wt2, a1, b1, a2, b2, gap);
  }
  {  // K4
    dim3 grid(HEAD_ / 256, N_);
    k4_head<<<grid, 256, 0, stream>>>(gap, wh, ah, bh, out);
  }
}